// Round 2
// baseline (1385.371 us; speedup 1.0000x reference)
//
#include <hip/hip_runtime.h>
#include <math.h>

// Problem constants (B=16, N=128, D=64, T=96)
#define BN   2048   // B*N
#define BN2  4096   // 2*B*N
#define DD   64
#define TT   96
#define NCH  128    // N (series channel stride)
#define RPB  8      // rows per block
#define TPB  256
#define NBLK (BN2 / RPB)   // 512

// ws layout (in floats):
//  ST   [BN][TT]   transposed series (row-contiguous, float4-aligned)
//  SSQ  [BN]       per-series-row sum of squares
//  SPEC [BN2][4]   per-row special terms {e1, snd1, e2, snd2}
//  PART [NBLK]     float2 partials
#define ST_OFF   0
#define SSQ_OFF  (BN * TT)
#define SPEC_OFF (SSQ_OFF + BN)
#define PART_OFF (SPEC_OFF + BN2 * 4)

__device__ __forceinline__ void smax_merge(float& m, float& s, float mo, float so) {
  float nm = fmaxf(m, mo);
  s = s * __expf(m - nm) + so * __expf(mo - nm);
  m = nm;
}

// ---------------- prep: transpose series, ssq, special terms ----------------
__global__ __launch_bounds__(TPB) void k_prep(
    const float* __restrict__ of, const float* __restrict__ af,
    const float* __restrict__ os, float* __restrict__ ws)
{
  float* ST  = ws + ST_OFF;
  float* SSQ = ws + SSQ_OFF;
  float* SPEC= ws + SPEC_OFF;
  const int b = blockIdx.x, tid = threadIdx.x;

  if (b < 768) {                       // transpose: 768*256 = 196608 = BN*TT
    int g = b * TPB + tid;
    int p = g / TT;
    int t = g - p * TT;
    ST[g] = os[((p >> 7) * TT + t) * NCH + (p & (NCH - 1))];
  } else if (b < 776) {                // ssq: 8*256 = 2048
    int p = (b - 768) * TPB + tid;
    const float* sp = os + (p >> 7) * TT * NCH + (p & (NCH - 1));
    float acc = 0.f;
    for (int t = 0; t < TT; ++t) { float v = sp[t * NCH]; acc = fmaf(v, v, acc); }
    SSQ[p] = acc;
  } else {                             // spec: 16*256 = 4096 rows
    int i = (b - 776) * TPB + tid;
    const float* fi = (i < BN) ? of + (size_t)i * DD : af + (size_t)(i - BN) * DD;
    float e1 = 0.f, snd1 = 0.f, e2 = 0.f, snd2 = 0.f;
    if (i >= 1) {
      const float* f1 = (i - 1 < BN) ? of + (size_t)(i - 1) * DD : af + (size_t)(i - 1 - BN) * DD;
      float sii = 0.f, sim1 = 0.f;
      for (int d = 0; d < DD; ++d) {
        sii  = fmaf(fi[d], fi[d], sii);
        sim1 = fmaf(fi[d], f1[d], sim1);
      }
      int p  = i & (BN - 1), p1 = (i - 1) & (BN - 1);
      const float* spv = os + (p  >> 7) * TT * NCH + (p  & (NCH - 1));
      const float* sp1 = os + (p1 >> 7) * TT * NCH + (p1 & (NCH - 1));
      float d1 = 0.f;
      for (int t = 0; t < TT; ++t) { float u = spv[t * NCH] - sp1[t * NCH]; d1 = fmaf(u, u, d1); }
      float slm1 = 1.f / (1.f + __expf(0.5f * d1));
      e2 = sim1 + sii; snd2 = slm1 + 0.5f;        // sl[i][i] = sigmoid(0) = 0.5
      if (i >= 2) {
        const float* f2 = (i - 2 < BN) ? of + (size_t)(i - 2) * DD : af + (size_t)(i - 2 - BN) * DD;
        float sim2 = 0.f;
        for (int d = 0; d < DD; ++d) sim2 = fmaf(fi[d], f2[d], sim2);
        int p2 = (i - 2) & (BN - 1);
        const float* sp2 = os + (p2 >> 7) * TT * NCH + (p2 & (NCH - 1));
        float d2 = 0.f;
        for (int t = 0; t < TT; ++t) { float u = spv[t * NCH] - sp2[t * NCH]; d2 = fmaf(u, u, d2); }
        float slm2 = 1.f / (1.f + __expf(0.5f * d2));
        e1 = sim2 + sim1; snd1 = slm2 + slm1;
      }
    }
    *(float4*)(SPEC + (size_t)i * 4) = make_float4(e1, snd1, e2, snd2);
  }
}

// ---------------- main: per-row online accumulation ----------------
__global__ __launch_bounds__(TPB, 4) void k_rows(
    const float* __restrict__ of, const float* __restrict__ af,
    float* __restrict__ ws)
{
  const float* ST  = ws + ST_OFF;
  const float* SSQ = ws + SSQ_OFF;
  const float* SPEC= ws + SPEC_OFF;
  float2* part = (float2*)(ws + PART_OFF);

  __shared__ float fR[RPB][DD];
  __shared__ float sR[RPB][TT];
  __shared__ float ssqR[RPB];
  __shared__ float redm[4][RPB], reds[4][RPB], redA[4][RPB], redB[4][RPB];
  __shared__ float redsl[4];
  __shared__ float rowloss[RPB];

  const int tid = threadIdx.x;
  const int i0 = blockIdx.x * RPB;
  const int p0 = i0 & (BN - 1);

  for (int idx = tid; idx < RPB * DD; idx += TPB) {
    int r = idx >> 6, d = idx & 63;
    int i = i0 + r;
    fR[r][d] = (i < BN) ? of[(size_t)i * DD + d] : af[(size_t)(i - BN) * DD + d];
  }
  for (int idx = tid; idx < RPB * TT; idx += TPB) {
    sR[idx / TT][idx % TT] = ST[(size_t)p0 * TT + idx];
  }
  if (tid < RPB) ssqR[tid] = SSQ[p0 + tid];
  __syncthreads();

  float m[RPB], s[RPB], Aa[RPB], Bb[RPB];
#pragma unroll
  for (int r = 0; r < RPB; ++r) { m[r] = 0.f; s[r] = 0.f; Aa[r] = 0.f; Bb[r] = 0.f; }
  float slsum = 0.f;

  for (int cb = 0; cb < BN; cb += TPB) {
    const int c = cb + tid;
    // feature dots, both halves
    float a0[RPB], a1[RPB];
#pragma unroll
    for (int r = 0; r < RPB; ++r) { a0[r] = 0.f; a1[r] = 0.f; }
    const float4* pc0 = (const float4*)(of + (size_t)c * DD);
    const float4* pc1 = (const float4*)(af + (size_t)c * DD);
#pragma unroll
    for (int d4 = 0; d4 < DD / 4; ++d4) {
      float4 a = pc0[d4], b = pc1[d4];
#pragma unroll
      for (int r = 0; r < RPB; ++r) {
        const float4 f = *(const float4*)(&fR[r][d4 * 4]);
        a0[r] = fmaf(a.x, f.x, fmaf(a.y, f.y, fmaf(a.z, f.z, fmaf(a.w, f.w, a0[r]))));
        a1[r] = fmaf(b.x, f.x, fmaf(b.y, f.y, fmaf(b.z, f.z, fmaf(b.w, f.w, a1[r]))));
      }
    }
    // series dot (shared by both halves)
    float sd[RPB];
#pragma unroll
    for (int r = 0; r < RPB; ++r) sd[r] = 0.f;
    const float4* pst = (const float4*)(ST + (size_t)c * TT);
#pragma unroll
    for (int t4 = 0; t4 < TT / 4; ++t4) {
      float4 v = pst[t4];
#pragma unroll
      for (int r = 0; r < RPB; ++r) {
        const float4 q = *(const float4*)(&sR[r][t4 * 4]);
        sd[r] = fmaf(v.x, q.x, fmaf(v.y, q.y, fmaf(v.z, q.z, fmaf(v.w, q.w, sd[r]))));
      }
    }
    const float ssq_c = SSQ[c];

#pragma unroll
    for (int r = 0; r < RPB; ++r) {
      const int i = i0 + r;
      const float dist = ssqR[r] + ssq_c - 2.f * sd[r];
      const float slv = __builtin_amdgcn_rcpf(1.f + __expf(0.5f * dist));
      slsum += 2.f * slv;                          // both column halves, unmasked count
      const bool msk0 = (c >= i - 2) && (c <= i);
      const bool msk1 = (c + BN >= i - 2) && (c + BN <= i);
      const float v0 = msk0 ? -1e30f : a0[r];
      const float v1 = msk1 ? -1e30f : a1[r];
      const float vm = fmaxf(v0, v1);
      if (vm > m[r] + 10.f) { s[r] *= __expf(m[r] - vm); m[r] = vm; }
      s[r] += __expf(v0 - m[r]) + __expf(v1 - m[r]);
      const float sl0 = msk0 ? 0.f : slv;
      const float sl1 = msk1 ? 0.f : slv;
      Aa[r] += sl0 + sl1;
      Bb[r] = fmaf(a0[r], sl0, fmaf(a1[r], sl1, Bb[r]));
    }
  }

  // wave butterfly reduce
#pragma unroll
  for (int off = 32; off; off >>= 1) {
#pragma unroll
    for (int r = 0; r < RPB; ++r) {
      float mo = __shfl_xor(m[r], off);
      float so = __shfl_xor(s[r], off);
      smax_merge(m[r], s[r], mo, so);
      Aa[r] += __shfl_xor(Aa[r], off);
      Bb[r] += __shfl_xor(Bb[r], off);
    }
    slsum += __shfl_xor(slsum, off);
  }
  const int w = tid >> 6;
  if ((tid & 63) == 0) {
#pragma unroll
    for (int r = 0; r < RPB; ++r) { redm[w][r] = m[r]; reds[w][r] = s[r]; redA[w][r] = Aa[r]; redB[w][r] = Bb[r]; }
    redsl[w] = slsum;
  }
  __syncthreads();

  if (tid < RPB) {
    const int r = tid;
    float M = redm[0][r], S = reds[0][r], Av = redA[0][r], Bv = redB[0][r];
    for (int ww = 1; ww < 4; ++ww) {
      smax_merge(M, S, redm[ww][r], reds[ww][r]);
      Av += redA[ww][r]; Bv += redB[ww][r];
    }
    const int i = i0 + r;
    const float4 sp = *(const float4*)(SPEC + (size_t)i * 4);  // e1,snd1,e2,snd2
    if (i >= 2) { smax_merge(M, S, sp.x, 1.f); Av += sp.y; Bv = fmaf(sp.x, sp.y, Bv); }
    if (i >= 1) { smax_merge(M, S, sp.z, 1.f); Av += sp.w; Bv = fmaf(sp.z, sp.w, Bv); }
    const float lse = M + logf(S);
    rowloss[r] = lse * Av - Bv;
  }
  __syncthreads();
  if (tid == 0) {
    float L = 0.f;
#pragma unroll
    for (int r = 0; r < RPB; ++r) L += rowloss[r];
    part[blockIdx.x] = make_float2(L, redsl[0] + redsl[1] + redsl[2] + redsl[3]);
  }
}

__global__ __launch_bounds__(TPB) void k_final(const float* __restrict__ ws,
                                               float* __restrict__ out)
{
  const float2* part = (const float2*)(ws + PART_OFF);
  __shared__ float sl_[TPB], sm_[TPB];
  const int tid = threadIdx.x;
  float L = 0.f, S = 0.f;
  for (int b = tid; b < NBLK; b += TPB) { L += part[b].x; S += part[b].y; }
  sl_[tid] = L; sm_[tid] = S;
  __syncthreads();
  for (int off = TPB / 2; off; off >>= 1) {
    if (tid < off) { sl_[tid] += sl_[tid + off]; sm_[tid] += sm_[tid + off]; }
    __syncthreads();
  }
  if (tid == 0) {
    out[0] = sl_[0] / (float)((long long)BN2 * (BN2 - 1));
    out[1] = sm_[0] / (float)((long long)BN2 * BN2);
  }
}

extern "C" void kernel_launch(void* const* d_in, const int* in_sizes, int n_in,
                              void* d_out, int out_size, void* d_ws, size_t ws_size,
                              hipStream_t stream) {
  (void)in_sizes; (void)n_in; (void)out_size; (void)ws_size;
  const float* of = (const float*)d_in[0];   // original_feature  (16,128,64)
  const float* af = (const float*)d_in[1];   // augmented_feature (16,128,64)
  const float* os = (const float*)d_in[2];   // original_series   (16,96,128)
  float* ws = (float*)d_ws;
  k_prep<<<792, TPB, 0, stream>>>(of, af, os, ws);
  k_rows<<<NBLK, TPB, 0, stream>>>(of, af, ws);
  k_final<<<1, TPB, 0, stream>>>(ws, (float*)d_out);
}

// Round 3
// 166.099 us; speedup vs baseline: 8.3406x; 8.3406x over previous
//
#include <hip/hip_runtime.h>
#include <math.h>

// Problem constants (B=16, N=128, D=64, T=96)
#define BN   2048
#define BN2  4096
#define DD   64
#define TT   96
#define NCH  128
#define RPB  8
#define TPB  256
#define NCHUNK 4
#define CHUNK  512                 // columns per block
#define NRG  (BN2 / RPB)           // 512 row-groups
#define NBLK (NRG * NCHUNK)        // 2048 blocks

// ws layout (floats)
#define ST_OFF   0
#define SSQ_OFF  (BN * TT)
#define SPEC_OFF (SSQ_OFF + BN)
#define SR_OFF   (SPEC_OFF + BN2 * 4)
#define AR_OFF   (SR_OFF + BN2 * NCHUNK)
#define BR_OFF   (AR_OFF + BN2 * NCHUNK)
#define SL_OFF   (BR_OFF + BN2 * NCHUNK)
// total = 266240 floats ≈ 1.04 MB

__device__ __forceinline__ void smax_merge(float& m, float& s, float mo, float so) {
  float nm = fmaxf(m, mo);
  s = s * __expf(m - nm) + so * __expf(mo - nm);
  m = nm;
}

// ---------------- prep: transpose series, ssq, special terms ----------------
__global__ __launch_bounds__(TPB) void k_prep(
    const float* __restrict__ of, const float* __restrict__ af,
    const float* __restrict__ os, float* __restrict__ ws)
{
  float* ST  = ws + ST_OFF;
  float* SSQ = ws + SSQ_OFF;
  float* SPEC= ws + SPEC_OFF;
  const int b = blockIdx.x, tid = threadIdx.x;

  if (b < 768) {                       // transpose: 768*256 = BN*TT
    int g = b * TPB + tid;
    int p = g / TT;
    int t = g - p * TT;
    ST[g] = os[((p >> 7) * TT + t) * NCH + (p & (NCH - 1))];
  } else if (b < 776) {                // ssq
    int p = (b - 768) * TPB + tid;
    const float* sp = os + (p >> 7) * TT * NCH + (p & (NCH - 1));
    float acc = 0.f;
    for (int t = 0; t < TT; ++t) { float v = sp[t * NCH]; acc = fmaf(v, v, acc); }
    SSQ[p] = acc;
  } else {                             // spec terms for 4096 rows
    int i = (b - 776) * TPB + tid;
    const float* fi = (i < BN) ? of + (size_t)i * DD : af + (size_t)(i - BN) * DD;
    float e1 = 0.f, snd1 = 0.f, e2 = 0.f, snd2 = 0.f;
    if (i >= 1) {
      const float* f1 = (i - 1 < BN) ? of + (size_t)(i - 1) * DD : af + (size_t)(i - 1 - BN) * DD;
      float sii = 0.f, sim1 = 0.f;
      for (int d = 0; d < DD; ++d) {
        sii  = fmaf(fi[d], fi[d], sii);
        sim1 = fmaf(fi[d], f1[d], sim1);
      }
      int p  = i & (BN - 1), p1 = (i - 1) & (BN - 1);
      const float* spv = os + (p  >> 7) * TT * NCH + (p  & (NCH - 1));
      const float* sp1 = os + (p1 >> 7) * TT * NCH + (p1 & (NCH - 1));
      float d1 = 0.f;
      for (int t = 0; t < TT; ++t) { float u = spv[t * NCH] - sp1[t * NCH]; d1 = fmaf(u, u, d1); }
      float slm1 = 1.f / (1.f + __expf(0.5f * d1));
      e2 = sim1 + sii; snd2 = slm1 + 0.5f;        // sl[i][i] = sigmoid(0) = 0.5
      if (i >= 2) {
        const float* f2 = (i - 2 < BN) ? of + (size_t)(i - 2) * DD : af + (size_t)(i - 2 - BN) * DD;
        float sim2 = 0.f;
        for (int d = 0; d < DD; ++d) sim2 = fmaf(fi[d], f2[d], sim2);
        int p2 = (i - 2) & (BN - 1);
        const float* sp2 = os + (p2 >> 7) * TT * NCH + (p2 & (NCH - 1));
        float d2 = 0.f;
        for (int t = 0; t < TT; ++t) { float u = spv[t * NCH] - sp2[t * NCH]; d2 = fmaf(u, u, d2); }
        float slm2 = 1.f / (1.f + __expf(0.5f * d2));
        e1 = sim2 + sim1; snd1 = slm2 + slm1;
      }
    }
    *(float4*)(SPEC + (size_t)i * 4) = make_float4(e1, snd1, e2, snd2);
  }
}

// ---------------- main: 8 rows x 512 cols per block ----------------
__global__ __launch_bounds__(TPB, 3) void k_rows(
    const float* __restrict__ of, const float* __restrict__ af,
    float* __restrict__ ws)
{
  const float* ST  = ws + ST_OFF;
  const float* SSQ = ws + SSQ_OFF;
  float* SR = ws + SR_OFF;
  float* AR = ws + AR_OFF;
  float* BR = ws + BR_OFF;
  float* SL = ws + SL_OFF;

  __shared__ float redS[4][RPB], redA[4][RPB], redB[4][RPB], redsl[4];

  const int tid = threadIdx.x;
  const int rg = blockIdx.x >> 2, chunk = blockIdx.x & 3;
  const int i0 = rg * RPB;
  const int c0 = chunk * CHUNK;
  const int p0 = i0 & (BN - 1);

  // block-uniform row pointers -> scalar loads in the inner loops
  const float* frow[RPB];
  const float* srow[RPB];
  float ssqR[RPB];
#pragma unroll
  for (int r = 0; r < RPB; ++r) {
    const int i = i0 + r;
    frow[r] = (i < BN) ? of + (size_t)i * DD : af + (size_t)(i - BN) * DD;
    srow[r] = ST + (size_t)(p0 + r) * TT;
    ssqR[r] = SSQ[p0 + r];
  }

  float s[RPB], Aa[RPB], Bb[RPB];
#pragma unroll
  for (int r = 0; r < RPB; ++r) { s[r] = 0.f; Aa[r] = 0.f; Bb[r] = 0.f; }
  float slsum = 0.f;

  for (int cb = 0; cb < CHUNK; cb += TPB) {
    const int c = c0 + cb + tid;

    float a0[RPB], a1[RPB];
#pragma unroll
    for (int r = 0; r < RPB; ++r) { a0[r] = 0.f; a1[r] = 0.f; }
    const float4* pc0 = (const float4*)(of + (size_t)c * DD);
    const float4* pc1 = (const float4*)(af + (size_t)c * DD);
#pragma unroll 4
    for (int d4 = 0; d4 < DD / 4; ++d4) {
      float4 a = pc0[d4], b = pc1[d4];
#pragma unroll
      for (int r = 0; r < RPB; ++r) {
        const float4 f = *(const float4*)(frow[r] + d4 * 4);   // uniform -> s_load
        a0[r] = fmaf(a.x, f.x, fmaf(a.y, f.y, fmaf(a.z, f.z, fmaf(a.w, f.w, a0[r]))));
        a1[r] = fmaf(b.x, f.x, fmaf(b.y, f.y, fmaf(b.z, f.z, fmaf(b.w, f.w, a1[r]))));
      }
    }

    float sd[RPB];
#pragma unroll
    for (int r = 0; r < RPB; ++r) sd[r] = 0.f;
    const float4* pst = (const float4*)(ST + (size_t)c * TT);
#pragma unroll 4
    for (int t4 = 0; t4 < TT / 4; ++t4) {
      float4 v = pst[t4];
#pragma unroll
      for (int r = 0; r < RPB; ++r) {
        const float4 q = *(const float4*)(srow[r] + t4 * 4);   // uniform -> s_load
        sd[r] = fmaf(v.x, q.x, fmaf(v.y, q.y, fmaf(v.z, q.z, fmaf(v.w, q.w, sd[r]))));
      }
    }
    const float ssq_c = SSQ[c];

#pragma unroll
    for (int r = 0; r < RPB; ++r) {
      const int i = i0 + r;
      const float dist = ssqR[r] + ssq_c - 2.f * sd[r];
      const float slv = __builtin_amdgcn_rcpf(1.f + __expf(0.5f * dist));
      slsum += 2.f * slv;
      const bool m0 = (unsigned)(c - i + 2) <= 2u;          // c in [i-2, i]
      const bool m1 = (unsigned)(c + BN - i + 2) <= 2u;
      const float v0 = m0 ? -1e30f : a0[r];
      const float v1 = m1 ? -1e30f : a1[r];
      s[r] += __expf(v0) + __expf(v1);                       // fixed max = 0
      const float sl0 = m0 ? 0.f : slv;
      const float sl1 = m1 ? 0.f : slv;
      Aa[r] += sl0 + sl1;
      Bb[r] = fmaf(a0[r], sl0, fmaf(a1[r], sl1, Bb[r]));
    }
  }

  // wave butterfly reduce
#pragma unroll
  for (int off = 32; off; off >>= 1) {
#pragma unroll
    for (int r = 0; r < RPB; ++r) {
      s[r]  += __shfl_xor(s[r],  off);
      Aa[r] += __shfl_xor(Aa[r], off);
      Bb[r] += __shfl_xor(Bb[r], off);
    }
    slsum += __shfl_xor(slsum, off);
  }
  const int w = tid >> 6;
  if ((tid & 63) == 0) {
#pragma unroll
    for (int r = 0; r < RPB; ++r) { redS[w][r] = s[r]; redA[w][r] = Aa[r]; redB[w][r] = Bb[r]; }
    redsl[w] = slsum;
  }
  __syncthreads();

  if (tid < RPB) {
    const int r = tid;
    float Sv = redS[0][r] + redS[1][r] + redS[2][r] + redS[3][r];
    float Av = redA[0][r] + redA[1][r] + redA[2][r] + redA[3][r];
    float Bv = redB[0][r] + redB[1][r] + redB[2][r] + redB[3][r];
    const int i = i0 + r;
    SR[(size_t)i * NCHUNK + chunk] = Sv;
    AR[(size_t)i * NCHUNK + chunk] = Av;
    BR[(size_t)i * NCHUNK + chunk] = Bv;
  }
  if (tid == 0) SL[blockIdx.x] = redsl[0] + redsl[1] + redsl[2] + redsl[3];
}

// ---------------- final: merge chunks, spec terms, reduce ----------------
__global__ __launch_bounds__(1024) void k_final(const float* __restrict__ ws,
                                                float* __restrict__ out)
{
  const float* SR = ws + SR_OFF;
  const float* AR = ws + AR_OFF;
  const float* BR = ws + BR_OFF;
  const float* SL = ws + SL_OFF;
  const float* SPEC = ws + SPEC_OFF;
  __shared__ float redL[1024], redS[1024];
  const int tid = threadIdx.x;

  float loss = 0.f;
#pragma unroll
  for (int t = 0; t < 4; ++t) {
    const int i = t * 1024 + tid;
    float Sv = 0.f, Av = 0.f, Bv = 0.f;
#pragma unroll
    for (int k = 0; k < NCHUNK; ++k) {
      Sv += SR[(size_t)i * NCHUNK + k];
      Av += AR[(size_t)i * NCHUNK + k];
      Bv += BR[(size_t)i * NCHUNK + k];
    }
    const float4 sp = *(const float4*)(SPEC + (size_t)i * 4);  // e1,snd1,e2,snd2
    float M = 0.f, S = Sv;
    if (i >= 2) { smax_merge(M, S, sp.x, 1.f); Av += sp.y; Bv = fmaf(sp.x, sp.y, Bv); }
    if (i >= 1) { smax_merge(M, S, sp.z, 1.f); Av += sp.w; Bv = fmaf(sp.z, sp.w, Bv); }
    loss += (M + logf(S)) * Av - Bv;
  }
  float sl = SL[tid] + SL[tid + 1024];

  redL[tid] = loss; redS[tid] = sl;
  __syncthreads();
  for (int off = 512; off; off >>= 1) {
    if (tid < off) { redL[tid] += redL[tid + off]; redS[tid] += redS[tid + off]; }
    __syncthreads();
  }
  if (tid == 0) {
    out[0] = redL[0] / (float)((long long)BN2 * (BN2 - 1));
    out[1] = redS[0] / (float)((long long)BN2 * BN2);
  }
}

extern "C" void kernel_launch(void* const* d_in, const int* in_sizes, int n_in,
                              void* d_out, int out_size, void* d_ws, size_t ws_size,
                              hipStream_t stream) {
  (void)in_sizes; (void)n_in; (void)out_size; (void)ws_size;
  const float* of = (const float*)d_in[0];   // original_feature  (16,128,64)
  const float* af = (const float*)d_in[1];   // augmented_feature (16,128,64)
  const float* os = (const float*)d_in[2];   // original_series   (16,96,128)
  float* ws = (float*)d_ws;
  k_prep<<<792, TPB, 0, stream>>>(of, af, os, ws);
  k_rows<<<NBLK, TPB, 0, stream>>>(of, af, ws);
  k_final<<<1, 1024, 0, stream>>>(ws, (float*)d_out);
}